// Round 7
// baseline (257.907 us; speedup 1.0000x reference)
//
#include <hip/hip_runtime.h>
#include <cstdint>
#include <cmath>

#define V_SIZE 50257
#define T_SIZE 2048
#define B_SIZE 512
#define CAND_MAX 1024
#define SPEC_THRESH 10.0f
#define SPEC_MIN 80
#define KOFF 32.0f

#define NTHR 1024
#define NWAVE (NTHR / 64)

#define BM_WORDS ((V_SIZE + 31) / 32)

// ---------------------------------------------------------------------------
// Fused kernel, v2: the prev-token pass (bitmap + dedup'd expsum correction)
// now runs AFTER the streaming pass. R6 profiling showed running it first
// cost +43MB FETCH (scattered lrow[v] on a cold cache) and serialized a
// latency stage before the stream; after the stream the row is L3-resident
// so the same scattered reads are L3 hits. No new barrier needed: nothing in
// the stream reads the bitmap, and the existing post-stream barrier covers
// both the candidate list and the bitmap.
//   phase A: pure stream: plain expsum + speculative candidates (x > 10)
//   phase B: prev bitmap + dedup'd correction (L3-warm scattered reads)
//   phase C: fix penalties on candidates; M from candidates; Z from corrected sum
//   phase D: bitonic sort — register/shfl_xor for j<64, LDS for j>=64
//   phase E: top-p/top-k decision (serial, order-preserving), softmax, scatter,
//            gumbel-argmax sample.
// Bisection fallback (~never) self-contained, reuses the phase-B bitmap.
// ---------------------------------------------------------------------------
extern "C" __global__ __launch_bounds__(NTHR, 8)
void fused_kernel(const float* __restrict__ logits,
                  const int*   __restrict__ prev,
                  const float* __restrict__ rand_u,
                  const float* __restrict__ tempp,
                  const float* __restrict__ toppp,
                  const float* __restrict__ repp,
                  float* __restrict__ out)
{
    const int row  = blockIdx.x;
    const int tid  = threadIdx.x;
    const int lane = tid & 63;
    const int wid  = tid >> 6;

    __shared__ unsigned int bitmap[BM_WORDS];
    __shared__ float cval[CAND_MAX];
    __shared__ int   cidx[CAND_MAX];
    __shared__ float rbuf[CAND_MAX];
    __shared__ float redf[NWAVE];
    __shared__ float redm[NWAVE];
    __shared__ int   redi[NWAVE];
    __shared__ float sM, sZ, sS, sStot;
    __shared__ int   sCnt, sSend;

    const float rp   = repp[0];
    const float topp = toppp[0];
    const float temp = fmaxf(tempp[0], 1e-5f);

    const size_t rowoff = (size_t)row * V_SIZE;
    const float* lrow = logits + rowoff;
    const float* urow = rand_u + rowoff;
    float*       orow = out + B_SIZE + rowoff;

    // ---- init LDS ----
    for (int i = tid; i < BM_WORDS; i += NTHR) bitmap[i] = 0u;
    if (tid == 0) sCnt = 0;
    __syncthreads();

    // ---- phase A: plain stream (no bitmap reads, no penalty, no max) ----
    const int head  = (4 - (row & 3)) & 3;     // V%4==1 -> row*V mod 4 == row mod 4
    const int nvec  = (V_SIZE - head) >> 2;
    const int tails = head + nvec * 4;
    const float4* lrow4 = (const float4*)(lrow + head);

    float lz0 = 0.0f, lz1 = 0.0f;
    auto collect = [&](float x, int v) {
        if (x > SPEC_THRESH) {
            int p = atomicAdd(&sCnt, 1);
            if (p < CAND_MAX) { cval[p] = x; cidx[p] = v; }
        }
    };
    if (tid < head) {
        float x = lrow[tid];
        collect(x, tid);
        lz0 += __expf(x - KOFF);
    }
    if (tid < V_SIZE - tails) {
        float x = lrow[tails + tid];
        collect(x, tails + tid);
        lz0 += __expf(x - KOFF);
    }
    for (int i = tid; i < nvec; i += NTHR) {
        float4 x4 = lrow4[i];
        int v = head + i * 4;
        collect(x4.x, v);     collect(x4.y, v + 1);
        collect(x4.z, v + 2); collect(x4.w, v + 3);
        lz0 += __expf(x4.x - KOFF) + __expf(x4.z - KOFF);
        lz1 += __expf(x4.y - KOFF) + __expf(x4.w - KOFF);
    }

    // ---- phase B: prev bitmap + dedup'd correction (row now L3-resident,
    //      so the scattered lrow[v] reads are cache hits) ----
    const int* prow = prev + (size_t)row * T_SIZE;
    float corr = 0.0f;
    for (int i = tid; i < T_SIZE; i += NTHR) {
        int v = prow[i];
        unsigned bit = 1u << (v & 31);
        unsigned old = atomicOr(&bitmap[((unsigned)v) >> 5], bit);
        if (!(old & bit)) {                    // first setter owns the correction
            float x  = lrow[v];
            float xp = (x < 0.0f) ? x * rp : x / rp;   // exact division
            corr += __expf(xp - KOFF) - __expf(x - KOFF);
        }
    }
    __syncthreads();                           // bitmap + candidate list complete

    // ---- phase C: fix candidate penalties; reduce sum; M over candidates ----
    const int Craw = sCnt;
    int C = min(Craw, CAND_MAX);
    for (int i = tid; i < C; i += NTHR) {
        int v = cidx[i];
        if ((bitmap[((unsigned)v) >> 5] >> (v & 31)) & 1u) {
            float x = cval[i];
            cval[i] = (x < 0.0f) ? x * rp : x / rp;
        }
    }
    {
        float wz = lz0 + lz1 + corr;
        for (int off = 32; off; off >>= 1) wz += __shfl_down(wz, off);
        if (lane == 0) redf[wid] = wz;
    }
    __syncthreads();                           // cval fixed + redf ready

    {
        float lm = -INFINITY;
        for (int i = tid; i < C; i += NTHR) lm = fmaxf(lm, cval[i]);
        for (int off = 32; off; off >>= 1) lm = fmaxf(lm, __shfl_down(lm, off));
        if (lane == 0) redm[wid] = lm;
    }
    __syncthreads();
    if (tid == 0) {
        float s = 0.0f, m = -INFINITY;
        for (int i = 0; i < NWAVE; ++i) { s += redf[i]; m = fmaxf(m, redm[i]); }
        sStot = s; sM = m;
    }
    __syncthreads();

    float M = sM;
    float Z = sStot * expf(KOFF - M);
    // exactness of the speculative path requires: count in range AND the fixed
    // candidate max clears the plain threshold (=> true row max is a candidate).
    bool ok = (Craw >= SPEC_MIN && Craw <= CAND_MAX && M > SPEC_THRESH);

    if (!ok) {
        // ---- fallback: full recompute with penalty inline (≈never);
        //      bitmap already built in phase B ----
        float lm = -INFINITY, lz = 0.0f;
        for (int v = tid; v < V_SIZE; v += NTHR) {
            float x = lrow[v];
            if ((bitmap[((unsigned)v) >> 5] >> (v & 31)) & 1u)
                x = (x < 0.0f) ? x * rp : x / rp;
            lm = fmaxf(lm, x);
            lz += __expf(x - KOFF);
        }
        {
            float wm = lm;
            for (int off = 32; off; off >>= 1) wm = fmaxf(wm, __shfl_down(wm, off));
            if (lane == 0) redm[wid] = wm;
        }
        __syncthreads();
        if (tid == 0) {
            float m = redm[0];
            for (int i = 1; i < NWAVE; ++i) m = fmaxf(m, redm[i]);
            sM = m;
        }
        __syncthreads();
        M = sM;
        {
            float wz = lz;
            for (int off = 32; off; off >>= 1) wz += __shfl_down(wz, off);
            if (lane == 0) redf[wid] = wz;
        }
        __syncthreads();
        if (tid == 0) {
            float s = 0.0f;
            for (int i = 0; i < NWAVE; ++i) s += redf[i];
            sZ = s * expf(KOFF - M);
        }
        __syncthreads();
        Z = sZ;

        auto count_pass = [&](float thr) -> int {
            __syncthreads();
            if (tid == 0) sCnt = 0;
            __syncthreads();
            int local = 0;
            for (int v = tid; v < V_SIZE; v += NTHR) {
                float x = lrow[v];
                if ((bitmap[((unsigned)v) >> 5] >> (v & 31)) & 1u)
                    x = (x < 0.0f) ? x * rp : x / rp;
                if (x > thr) local++;
            }
            if (local) atomicAdd(&sCnt, local);
            __syncthreads();
            return sCnt;
        };
        float a = -200.0f, b = 200.0f, thr = 0.0f;
        int c = 0;
        for (int it = 0; it < 40; ++it) {
            thr = 0.5f * (a + b);
            c = count_pass(thr);
            if (c < SPEC_MIN)       b = thr;
            else if (c > CAND_MAX)  a = thr;
            else break;
        }
        if (c < SPEC_MIN) thr = a;
        __syncthreads();
        if (tid == 0) sCnt = 0;
        __syncthreads();
        for (int v = tid; v < V_SIZE; v += NTHR) {
            float x = lrow[v];
            if ((bitmap[((unsigned)v) >> 5] >> (v & 31)) & 1u)
                x = (x < 0.0f) ? x * rp : x / rp;
            if (x > thr) {
                int p = atomicAdd(&sCnt, 1);
                if (p < CAND_MAX) { cval[p] = x; cidx[p] = v; }
            }
        }
        __syncthreads();
        C = min(sCnt, CAND_MAX);
    }

    // ---- phase D: bitonic sort, descending value, tie -> ascending index ----
    int n = 1; while (n < C) n <<= 1;          // n in [128,1024]; typ. 512
    for (int i = C + tid; i < n; i += NTHR) { cval[i] = -INFINITY; cidx[i] = 0x7FFFFFFF; }
    __syncthreads();

    if (n <= 512) {
        // register-resident: element t lives in thread t; shfl_xor for j<64
        // (partner in same wave since n is a multiple of 64), LDS for j>=64.
        // 'act' is wave-uniform, so barriers stay outside the guard and shfl
        // never runs on a partial wave.
        const int t = tid;
        const bool act = (t < n);
        float v = 0.0f; int id = 0;
        if (act) { v = cval[t]; id = cidx[t]; }
        for (int k = 2; k <= n; k <<= 1) {
            for (int j = k >> 1; j > 0; j >>= 1) {
                float pv = 0.0f; int pid = 0;
                if (j >= 64) {
                    __syncthreads();           // prior reads of cval/cidx done
                    if (act) { cval[t] = v; cidx[t] = id; }
                    __syncthreads();
                    if (act) { pv = cval[t ^ j]; pid = cidx[t ^ j]; }
                } else if (act) {
                    pv  = __shfl_xor(v, j);
                    pid = __shfl_xor(id, j);
                }
                if (act) {
                    const bool amLow = ((t & j) == 0);
                    const float vi = amLow ? v : pv,  vl = amLow ? pv : v;
                    const int   ii = amLow ? id : pid, il = amLow ? pid : id;
                    const bool lFirst = (vl > vi) || (vl == vi && il < ii);
                    const bool asc = ((t & k) == 0);
                    if (lFirst == asc) { v = pv; id = pid; }   // both take partner's
                }
            }
        }
        __syncthreads();
        if (act) { cval[t] = v; cidx[t] = id; }
        __syncthreads();
    } else {
        // n = 1024 (C > 512, ≈never): original LDS bitonic
        for (int k = 2; k <= n; k <<= 1) {
            for (int j = k >> 1; j > 0; j >>= 1) {
                for (int i = tid; i < n; i += NTHR) {
                    int l = i ^ j;
                    if (l > i) {
                        float vi = cval[i], vl = cval[l];
                        int   ii = cidx[i], il = cidx[l];
                        bool lFirst = (vl > vi) || (vl == vi && il < ii);
                        bool asc = ((i & k) == 0);
                        if (lFirst == asc) {
                            cval[i] = vl; cval[l] = vi;
                            cidx[i] = il; cidx[l] = ii;
                        }
                    }
                }
                __syncthreads();
            }
        }
    }

    // ---- phase E: decision (serial, order-preserving), softmax, scatter ----
    for (int i = tid; i < C; i += NTHR)
        rbuf[i] = expf(cval[i] - M) / Z;
    __syncthreads();

    if (tid == 0) {
        float cum = 0.0f;
        int m = 0;
        float vp = cval[min(49, C - 1)];
        for (int i = 0; i < C; ++i) {
            cum += rbuf[i];
            if (i > 0 && cum > topp) break;      // suffix removed; m final
            m = i;
            if (m >= 49 && cval[i] < vp) break;  // past pivot tie-run
        }
        int send;
        if (m >= 49) {
            int e = 49;
            while (e + 1 < C && cval[e + 1] == vp) ++e;
            send = (m < e) ? m : e;
        } else {
            send = m;
        }
        sSend = send;
    }
    __syncthreads();

    const int send = sSend;
    const float v0 = cval[0];
    for (int i = tid; i <= send; i += NTHR)
        rbuf[i] = expf(cval[i] / temp - v0 / temp);
    __syncthreads();
    if (tid == 0) {
        float S = 0.0f;
        for (int i = 0; i <= send; ++i) S += rbuf[i];
        sS = S;
    }
    __syncthreads();
    const float S = sS;

    float bestr = -1.0f;
    int   besti = 0x7FFFFFFF;
    for (int i = tid; i <= send; i += NTHR) {
        float p = rbuf[i] / S;
        int v = cidx[i];
        orow[v] = p;                             // memset provided the zeros
        float q = -logf(urow[v]);
        float r = p / q;
        if (r > bestr || (r == bestr && v < besti)) { bestr = r; besti = v; }
    }
    for (int off = 32; off; off >>= 1) {
        float r2 = __shfl_down(bestr, off);
        int   i2 = __shfl_down(besti, off);
        if (r2 > bestr || (r2 == bestr && i2 < besti)) { bestr = r2; besti = i2; }
    }
    if (lane == 0) { redf[wid] = bestr; redi[wid] = besti; }
    __syncthreads();
    if (tid == 0) {
        float br = redf[0]; int bi = redi[0];
        for (int i = 1; i < NWAVE; ++i) {
            if (redf[i] > br || (redf[i] == br && redi[i] < bi)) { br = redf[i]; bi = redi[i]; }
        }
        out[row] = (float)bi;                    // idx as f32 (exact for < 2^24)
    }
}

extern "C" void kernel_launch(void* const* d_in, const int* in_sizes, int n_in,
                              void* d_out, int out_size, void* d_ws, size_t ws_size,
                              hipStream_t stream) {
    const float* logits = (const float*)d_in[0];
    const int*   prev   = (const int*)d_in[1];
    const float* rand_u = (const float*)d_in[2];
    const float* tempp  = (const float*)d_in[3];
    const float* toppp  = (const float*)d_in[4];
    const float* repp   = (const float*)d_in[5];
    float* out = (float*)d_out;

    (void)hipMemsetAsync(d_out, 0, (size_t)out_size, stream);

    hipLaunchKernelGGL(fused_kernel, dim3(B_SIZE), dim3(NTHR), 0, stream,
                       logits, prev, rand_u, tempp, toppp, repp, out);
}

// Round 10
// 246.463 us; speedup vs baseline: 1.0464x; 1.0464x over previous
//
#include <hip/hip_runtime.h>
#include <cstdint>
#include <cmath>

#define V_SIZE 50257
#define T_SIZE 2048
#define B_SIZE 512
#define CAND_MAX 1024
#define SPEC_THRESH 10.0f
#define SPEC_MIN 80
#define KOFF 32.0f

#define NTHR 1024
#define NWAVE (NTHR / 64)

#define BM_WORDS ((V_SIZE + 31) / 32)

// ---------------------------------------------------------------------------
// Fused kernel, v3b (v3 + straddle fix).
// R6/R7 lesson: dedup'd scattered lrow[v] reads cost +43MB fetch in ANY
// position; the stream is latency-bound. So: penalty INLINE in the stream,
// stream manually batched x4 (4 float4 loads in flight per wave).
// v3 BUG: v = head + 4i is not 0 mod 4 for head!=0, so the 4 penalty bits can
// straddle two bitmap words ((v&31)>28) -> missed penalties -> wrong sample.
// FIX: bitmap padded +1 zero word; straddle-safe 64-bit bit extraction.
//   phase A: prev bitmap (atomicOr only, no logit reads)
//   phase B: stream x4-batched: inline penalty + expsum + candidates (x_f > 10)
//   phase C: M from candidates; Z from the (exact) streamed sum
//   phase D: bitonic sort - register/shfl_xor for j<64, LDS for j>=64
//   phase E: top-p/top-k decision, softmax, scatter, gumbel-argmax sample
// Bisection fallback (~never) self-contained, reuses the phase-A bitmap.
// ---------------------------------------------------------------------------
extern "C" __global__ __launch_bounds__(NTHR, 8)
void fused_kernel(const float* __restrict__ logits,
                  const int*   __restrict__ prev,
                  const float* __restrict__ rand_u,
                  const float* __restrict__ tempp,
                  const float* __restrict__ toppp,
                  const float* __restrict__ repp,
                  float* __restrict__ out)
{
    const int row  = blockIdx.x;
    const int tid  = threadIdx.x;
    const int lane = tid & 63;
    const int wid  = tid >> 6;

    __shared__ unsigned int bitmap[BM_WORDS + 1];   // +1 zero pad for straddle
    __shared__ float cval[CAND_MAX];
    __shared__ int   cidx[CAND_MAX];
    __shared__ float rbuf[CAND_MAX];
    __shared__ float redf[NWAVE];
    __shared__ float redm[NWAVE];
    __shared__ int   redi[NWAVE];
    __shared__ float sM, sZ, sS, sStot;
    __shared__ int   sCnt, sSend;

    const float rp   = repp[0];
    const float topp = toppp[0];
    const float temp = fmaxf(tempp[0], 1e-5f);

    const size_t rowoff = (size_t)row * V_SIZE;
    const float* lrow = logits + rowoff;
    const float* urow = rand_u + rowoff;
    float*       orow = out + B_SIZE + rowoff;

    // ---- init LDS ----
    for (int i = tid; i < BM_WORDS + 1; i += NTHR) bitmap[i] = 0u;
    if (tid == 0) sCnt = 0;
    __syncthreads();

    // ---- phase A: prev bitmap (atomicOr only; no scattered logit reads) ----
    const int* prow = prev + (size_t)row * T_SIZE;
    for (int i = tid; i < T_SIZE; i += NTHR) {
        int v = prow[i];
        atomicOr(&bitmap[((unsigned)v) >> 5], 1u << (v & 31));
    }
    __syncthreads();                           // bitmap complete before stream

    // ---- phase B: stream, x4-batched, penalty inline ----
    const int head  = (4 - (row & 3)) & 3;     // V%4==1 -> row*V mod 4 == row mod 4
    const int nvec  = (V_SIZE - head) >> 2;
    const int tails = head + nvec * 4;
    const float4* lrow4 = (const float4*)(lrow + head);

    float lz0 = 0.0f, lz1 = 0.0f;
    auto pen = [&](float x) { return (x < 0.0f) ? x * rp : x / rp; };  // exact div
    auto collect = [&](float x, int v) {
        if (x > SPEC_THRESH) {
            int p = atomicAdd(&sCnt, 1);
            if (p < CAND_MAX) { cval[p] = x; cidx[p] = v; }
        }
    };
    auto proc1 = [&](float x, int v) {
        unsigned w = bitmap[((unsigned)v) >> 5];
        if ((w >> (v & 31)) & 1u) x = pen(x);
        collect(x, v);
        lz0 += __expf(x - KOFF);
    };
    // 4 consecutive bits starting at v; may straddle two words (head != 0)
    auto proc4 = [&](float4 x4, int v) {
        const int wi = ((unsigned)v) >> 5;
        const unsigned sh = (unsigned)v & 31u;
        unsigned long long w64 =
            ((unsigned long long)bitmap[wi + 1] << 32) | (unsigned long long)bitmap[wi];
        unsigned w = (unsigned)(w64 >> sh);
        float a = x4.x, b = x4.y, c = x4.z, d = x4.w;
        if (w & 1u) a = pen(a);
        if (w & 2u) b = pen(b);
        if (w & 4u) c = pen(c);
        if (w & 8u) d = pen(d);
        collect(a, v); collect(b, v + 1); collect(c, v + 2); collect(d, v + 3);
        lz0 += __expf(a - KOFF) + __expf(c - KOFF);
        lz1 += __expf(b - KOFF) + __expf(d - KOFF);
    };

    if (tid < head)           proc1(lrow[tid], tid);
    if (tid < V_SIZE - tails) proc1(lrow[tails + tid], tails + tid);

    int i = tid;
    for (; i + 3 * NTHR < nvec; i += 4 * NTHR) {
        // 4 independent loads issued before any use -> 4 VMEM in flight/wave
        float4 a0 = lrow4[i];
        float4 a1 = lrow4[i + NTHR];
        float4 a2 = lrow4[i + 2 * NTHR];
        float4 a3 = lrow4[i + 3 * NTHR];
        proc4(a0, head + i * 4);
        proc4(a1, head + (i + NTHR) * 4);
        proc4(a2, head + (i + 2 * NTHR) * 4);
        proc4(a3, head + (i + 3 * NTHR) * 4);
    }
    for (; i < nvec; i += NTHR) proc4(lrow4[i], head + i * 4);

    __syncthreads();                           // candidates + sums complete

    // ---- phase C: reductions (sum + candidate max under one barrier) ----
    const int Craw = sCnt;
    int C = min(Craw, CAND_MAX);
    {
        float wz = lz0 + lz1;
        for (int off = 32; off; off >>= 1) wz += __shfl_down(wz, off);
        float lm = -INFINITY;
        for (int k = tid; k < C; k += NTHR) lm = fmaxf(lm, cval[k]);
        for (int off = 32; off; off >>= 1) lm = fmaxf(lm, __shfl_down(lm, off));
        if (lane == 0) { redf[wid] = wz; redm[wid] = lm; }
    }
    __syncthreads();
    if (tid == 0) {
        float s = 0.0f, m = -INFINITY;
        for (int k = 0; k < NWAVE; ++k) { s += redf[k]; m = fmaxf(m, redm[k]); }
        sStot = s; sM = m;
    }
    __syncthreads();

    float M = sM;
    float Z = sStot * expf(KOFF - M);
    // exactness of the speculative path: count in range AND candidate max
    // clears the threshold (=> true row max is among the candidates).
    bool ok = (Craw >= SPEC_MIN && Craw <= CAND_MAX && M > SPEC_THRESH);

    if (!ok) {
        // ---- fallback: full recompute with penalty inline (≈never);
        //      bitmap already built in phase A ----
        float lm = -INFINITY, lz = 0.0f;
        for (int v = tid; v < V_SIZE; v += NTHR) {
            float x = lrow[v];
            if ((bitmap[((unsigned)v) >> 5] >> (v & 31)) & 1u) x = pen(x);
            lm = fmaxf(lm, x);
            lz += __expf(x - KOFF);
        }
        {
            float wm = lm;
            for (int off = 32; off; off >>= 1) wm = fmaxf(wm, __shfl_down(wm, off));
            if (lane == 0) redm[wid] = wm;
        }
        __syncthreads();
        if (tid == 0) {
            float m = redm[0];
            for (int k = 1; k < NWAVE; ++k) m = fmaxf(m, redm[k]);
            sM = m;
        }
        __syncthreads();
        M = sM;
        {
            float wz = lz;
            for (int off = 32; off; off >>= 1) wz += __shfl_down(wz, off);
            if (lane == 0) redf[wid] = wz;
        }
        __syncthreads();
        if (tid == 0) {
            float s = 0.0f;
            for (int k = 0; k < NWAVE; ++k) s += redf[k];
            sZ = s * expf(KOFF - M);
        }
        __syncthreads();
        Z = sZ;

        auto count_pass = [&](float thr) -> int {
            __syncthreads();
            if (tid == 0) sCnt = 0;
            __syncthreads();
            int local = 0;
            for (int v = tid; v < V_SIZE; v += NTHR) {
                float x = lrow[v];
                if ((bitmap[((unsigned)v) >> 5] >> (v & 31)) & 1u) x = pen(x);
                if (x > thr) local++;
            }
            if (local) atomicAdd(&sCnt, local);
            __syncthreads();
            return sCnt;
        };
        float a = -200.0f, b = 200.0f, thr = 0.0f;
        int c = 0;
        for (int it = 0; it < 40; ++it) {
            thr = 0.5f * (a + b);
            c = count_pass(thr);
            if (c < SPEC_MIN)       b = thr;
            else if (c > CAND_MAX)  a = thr;
            else break;
        }
        if (c < SPEC_MIN) thr = a;
        __syncthreads();
        if (tid == 0) sCnt = 0;
        __syncthreads();
        for (int v = tid; v < V_SIZE; v += NTHR) {
            float x = lrow[v];
            if ((bitmap[((unsigned)v) >> 5] >> (v & 31)) & 1u) x = pen(x);
            if (x > thr) {
                int p = atomicAdd(&sCnt, 1);
                if (p < CAND_MAX) { cval[p] = x; cidx[p] = v; }
            }
        }
        __syncthreads();
        C = min(sCnt, CAND_MAX);
    }

    // ---- phase D: bitonic sort, descending value, tie -> ascending index ----
    int n = 1; while (n < C) n <<= 1;          // n in [128,1024]; typ. 512
    for (int k = C + tid; k < n; k += NTHR) { cval[k] = -INFINITY; cidx[k] = 0x7FFFFFFF; }
    __syncthreads();

    if (n <= 512) {
        // register-resident: element t lives in thread t; shfl_xor for j<64
        // (partner in same wave since n is a multiple of 64), LDS for j>=64.
        const int t = tid;
        const bool act = (t < n);
        float v = 0.0f; int id = 0;
        if (act) { v = cval[t]; id = cidx[t]; }
        for (int k = 2; k <= n; k <<= 1) {
            for (int j = k >> 1; j > 0; j >>= 1) {
                float pv = 0.0f; int pid = 0;
                if (j >= 64) {
                    __syncthreads();           // prior reads of cval/cidx done
                    if (act) { cval[t] = v; cidx[t] = id; }
                    __syncthreads();
                    if (act) { pv = cval[t ^ j]; pid = cidx[t ^ j]; }
                } else if (act) {
                    pv  = __shfl_xor(v, j);
                    pid = __shfl_xor(id, j);
                }
                if (act) {
                    const bool amLow = ((t & j) == 0);
                    const float vi = amLow ? v : pv,  vl = amLow ? pv : v;
                    const int   ii = amLow ? id : pid, il = amLow ? pid : id;
                    const bool lFirst = (vl > vi) || (vl == vi && il < ii);
                    const bool asc = ((t & k) == 0);
                    if (lFirst == asc) { v = pv; id = pid; }   // take partner's
                }
            }
        }
        __syncthreads();
        if (act) { cval[t] = v; cidx[t] = id; }
        __syncthreads();
    } else {
        // n = 1024 (C > 512, ≈never): LDS bitonic
        for (int k = 2; k <= n; k <<= 1) {
            for (int j = k >> 1; j > 0; j >>= 1) {
                for (int q = tid; q < n; q += NTHR) {
                    int l = q ^ j;
                    if (l > q) {
                        float vi = cval[q], vl = cval[l];
                        int   ii = cidx[q], il = cidx[l];
                        bool lFirst = (vl > vi) || (vl == vi && il < ii);
                        bool asc = ((q & k) == 0);
                        if (lFirst == asc) {
                            cval[q] = vl; cval[l] = vi;
                            cidx[q] = il; cidx[l] = ii;
                        }
                    }
                }
                __syncthreads();
            }
        }
    }

    // ---- phase E: decision (serial, order-preserving), softmax, scatter ----
    for (int k = tid; k < C; k += NTHR)
        rbuf[k] = expf(cval[k] - M) / Z;
    __syncthreads();

    if (tid == 0) {
        float cum = 0.0f;
        int m = 0;
        float vp = cval[min(49, C - 1)];
        for (int k = 0; k < C; ++k) {
            cum += rbuf[k];
            if (k > 0 && cum > topp) break;      // suffix removed; m final
            m = k;
            if (m >= 49 && cval[k] < vp) break;  // past pivot tie-run
        }
        int send;
        if (m >= 49) {
            int e = 49;
            while (e + 1 < C && cval[e + 1] == vp) ++e;
            send = (m < e) ? m : e;
        } else {
            send = m;
        }
        sSend = send;
    }
    __syncthreads();

    const int send = sSend;
    const float v0 = cval[0];
    for (int k = tid; k <= send; k += NTHR)
        rbuf[k] = expf(cval[k] / temp - v0 / temp);
    __syncthreads();
    if (tid == 0) {
        float S = 0.0f;
        for (int k = 0; k <= send; ++k) S += rbuf[k];
        sS = S;
    }
    __syncthreads();
    const float S = sS;

    float bestr = -1.0f;
    int   besti = 0x7FFFFFFF;
    for (int k = tid; k <= send; k += NTHR) {
        float p = rbuf[k] / S;
        int v = cidx[k];
        orow[v] = p;                             // memset provided the zeros
        float q = -logf(urow[v]);
        float r = p / q;
        if (r > bestr || (r == bestr && v < besti)) { bestr = r; besti = v; }
    }
    for (int off = 32; off; off >>= 1) {
        float r2 = __shfl_down(bestr, off);
        int   i2 = __shfl_down(besti, off);
        if (r2 > bestr || (r2 == bestr && i2 < besti)) { bestr = r2; besti = i2; }
    }
    if (lane == 0) { redf[wid] = bestr; redi[wid] = besti; }
    __syncthreads();
    if (tid == 0) {
        float br = redf[0]; int bi = redi[0];
        for (int k = 1; k < NWAVE; ++k) {
            if (redf[k] > br || (redf[k] == br && redi[k] < bi)) { br = redf[k]; bi = redi[k]; }
        }
        out[row] = (float)bi;                    // idx as f32 (exact for < 2^24)
    }
}

extern "C" void kernel_launch(void* const* d_in, const int* in_sizes, int n_in,
                              void* d_out, int out_size, void* d_ws, size_t ws_size,
                              hipStream_t stream) {
    const float* logits = (const float*)d_in[0];
    const int*   prev   = (const int*)d_in[1];
    const float* rand_u = (const float*)d_in[2];
    const float* tempp  = (const float*)d_in[3];
    const float* toppp  = (const float*)d_in[4];
    const float* repp   = (const float*)d_in[5];
    float* out = (float*)d_out;

    (void)hipMemsetAsync(d_out, 0, (size_t)out_size, stream);

    hipLaunchKernelGGL(fused_kernel, dim3(B_SIZE), dim3(NTHR), 0, stream,
                       logits, prev, rand_u, tempp, toppp, repp, out);
}